// Round 6
// baseline (2625.358 us; speedup 1.0000x reference)
//
#include <hip/hip_runtime.h>
#include <hip/hip_fp16.h>

// ---------------------------------------------------------------------------
// IABlockND, precision-hardened. B=128, C=1024, N=288.
// Channel-softmax logits have razor-thin data ties (|dL| sensitivity ~0.1),
// so the channel gram uses split-bf16 (hi+lo) 3-pass MFMA; the spatial AV
// GEMM uses split-x + split-F2 with fp16 y (BN1 amplifies y errors x17).
//
// Phases (batch-chunked to fit ~261 MB workspace):
//  P1 (8 chunks of 16 b): xsplit -> xh,xl,xT ; G1 gram (bf16, margin 31);
//     SM1 (softmax*dis->softmax) -> F2h,F2l ; G2 3-pass -> y (fp16)
//  P2: BN1 stats ; z_stage: z = y*a1+b1+x -> zh,zl (zl in-place over y)
//  P3 (8 chunks of 16 b): G3 3-pass split gram -> logits fp32 ; SM2 -> P bf16;
//     ztrans zh->zT ; G4: y2 = P . zT -> out
//  P4: BN2 stats ; final: out = out*a2+b2 + (zh+zl)
// ---------------------------------------------------------------------------

#define B_   128
#define C_   1024
#define NSP  288
#define CN   (C_*NSP)          // 294912
#define CC   (C_*C_)           // 1048576
#define SP2  (NSP*NSP)         // 82944
#define NE   ((size_t)B_*CN)   // 37748736
#define BC1  16                // phase-1 batch chunk
#define BC3  16                // phase-3 batch chunk

typedef float  v4f   __attribute__((ext_vector_type(4)));
typedef short  s16x8 __attribute__((ext_vector_type(8)));
typedef __bf16 bf8v  __attribute__((ext_vector_type(8)));

__device__ inline float bf2f(ushort u) {
    unsigned x = ((unsigned)u) << 16;
    return __builtin_bit_cast(float, x);
}
__device__ inline ushort f2bf(float f) {   // RNE
    unsigned x = __builtin_bit_cast(unsigned, f);
    unsigned r = (x + 0x7FFFu + ((x >> 16) & 1u)) >> 16;
    return (ushort)r;
}
__device__ inline v4f mfma_bf16(s16x8 a, s16x8 b, v4f c) {
    return __builtin_amdgcn_mfma_f32_16x16x32_bf16(
        __builtin_bit_cast(bf8v, a), __builtin_bit_cast(bf8v, b), c, 0, 0, 0);
}
__device__ inline float wredmax(float x) {
    #pragma unroll
    for (int o = 32; o >= 1; o >>= 1) x = fmaxf(x, __shfl_xor(x, o));
    return x;
}
__device__ inline float wredsum(float x) {
    #pragma unroll
    for (int o = 32; o >= 1; o >>= 1) x += __shfl_xor(x, o);
    return x;
}

// ---------------- P1a: x -> xh,xl (c-major) + xT (n-major), per chunk -------
__global__ __launch_bounds__(256) void xsplit(
        const float* __restrict__ x, ushort* __restrict__ xh,
        ushort* __restrict__ xl, ushort* __restrict__ xT, int b0)
{
    __shared__ float lds[32][289];
    const int c0 = blockIdx.x * 32, bb = blockIdx.y, b = b0 + bb;
    const size_t gbase = ((size_t)b * C_ + c0) * NSP;
    const size_t lbase = ((size_t)bb * C_ + c0) * NSP;
    for (int i = threadIdx.x; i < 32 * NSP; i += 256) {
        int cl = i / NSP, nl = i - cl * NSP;
        float v = x[gbase + (size_t)cl * NSP + nl];
        ushort h = f2bf(v);
        xh[lbase + (size_t)cl * NSP + nl] = h;
        xl[lbase + (size_t)cl * NSP + nl] = f2bf(v - bf2f(h));
        lds[cl][nl] = v;
    }
    __syncthreads();
    const size_t tbase = (size_t)bb * CN + c0;
    for (int i = threadIdx.x; i < NSP * 32; i += 256) {
        int nl = i >> 5, cl = i & 31;
        xT[tbase + (size_t)nl * C_ + cl] = f2bf(lds[cl][nl]);
    }
}

// ---------------- generic multi-pass NT GEMM --------------------------------
// acc over NP passes of D[m,n]+=sum_k A_p[m][k]*B_p[n][k]; OKIND 0=f32,1=bf16,2=f16
template<int TM, int TN, int OKIND, int NP>
__global__ __launch_bounds__(256) void gemm_nt(
        const ushort* A0, const ushort* B0, const ushort* A1, const ushort* B1,
        const ushort* A2, const ushort* B2, void* Ob, const int K, const int N,
        const long sA, const long sB, const long sO, const float scale)
{
    constexpr int WM = TM / 2, WN = TN / 2;
    constexpr int MFR = WM / 16, NFR = WN / 16;
    __shared__ __align__(16) ushort ldsA[TM * 40];
    __shared__ __align__(16) ushort ldsB[TN * 40];

    const int tid  = threadIdx.x;
    const int lane = tid & 63;
    const int w    = tid >> 6;
    const int wm   = w >> 1, wn = w & 1;
    const int quad = lane >> 4, r16 = lane & 15;
    const ushort* As[3] = {A0, A1, A2};
    const ushort* Bs[3] = {B0, B1, B2};

    v4f acc[MFR][NFR] = {};

    #pragma unroll
    for (int p = 0; p < NP; ++p) {
        const ushort* A  = As[p] + (size_t)blockIdx.z * sA + (size_t)blockIdx.y * TM * K;
        const ushort* Bp = Bs[p] + (size_t)blockIdx.z * sB + (size_t)blockIdx.x * TN * K;
        for (int k0 = 0; k0 < K; k0 += 32) {
            for (int i = tid; i < TM * 4; i += 256) {
                int rr = i >> 2, c4 = i & 3;
                *(uint4*)&ldsA[rr * 40 + c4 * 8] =
                    *(const uint4*)(A + (size_t)rr * K + k0 + c4 * 8);
            }
            for (int i = tid; i < TN * 4; i += 256) {
                int rr = i >> 2, c4 = i & 3;
                *(uint4*)&ldsB[rr * 40 + c4 * 8] =
                    *(const uint4*)(Bp + (size_t)rr * K + k0 + c4 * 8);
            }
            __syncthreads();
            s16x8 af[MFR], bfr[NFR];
            #pragma unroll
            for (int mi = 0; mi < MFR; mi++)
                af[mi] = *(const s16x8*)&ldsA[(wm * WM + mi * 16 + r16) * 40 + quad * 8];
            #pragma unroll
            for (int ni = 0; ni < NFR; ni++)
                bfr[ni] = *(const s16x8*)&ldsB[(wn * WN + ni * 16 + r16) * 40 + quad * 8];
            #pragma unroll
            for (int mi = 0; mi < MFR; mi++)
                #pragma unroll
                for (int ni = 0; ni < NFR; ni++)
                    acc[mi][ni] = mfma_bf16(af[mi], bfr[ni], acc[mi][ni]);
            __syncthreads();
        }
    }

    const size_t obase = (size_t)blockIdx.z * sO;
    const int row0 = blockIdx.y * TM + wm * WM;
    const int col0 = blockIdx.x * TN + wn * WN + r16;
    #pragma unroll
    for (int mi = 0; mi < MFR; mi++)
        #pragma unroll
        for (int ni = 0; ni < NFR; ni++)
            #pragma unroll
            for (int j = 0; j < 4; j++) {
                size_t o = obase + (size_t)(row0 + mi * 16 + quad * 4 + j) * N
                         + col0 + ni * 16;
                float v = acc[mi][ni][j] * scale;
                if (OKIND == 1)      ((ushort*)Ob)[o] = f2bf(v);
                else if (OKIND == 2) ((__half*)Ob)[o] = __float2half(v);
                else                 ((float*) Ob)[o] = v;
            }
}

// ---------------- SM1: softmax * dis -> softmax -> F2 hi+lo -----------------
__global__ __launch_bounds__(256) void softmax_spatial(
        const float* __restrict__ f, const float* __restrict__ dis,
        ushort* __restrict__ F2h, ushort* __restrict__ F2l)
{
    const int w = threadIdx.x >> 6, lane = threadIdx.x & 63;
    const size_t row = (size_t)blockIdx.x * 4 + w;
    const int p = (int)(row % NSP);
    const float* fr = f + row * NSP;
    const float* dr = dis + (size_t)p * NSP;
    const bool v4 = (lane < 32);

    float v[5];
    #pragma unroll
    for (int j = 0; j < 4; j++) v[j] = fr[lane + j * 64];
    v[4] = v4 ? fr[256 + lane] : -1e30f;
    float m = v[0];
    #pragma unroll
    for (int j = 1; j < 5; j++) m = fmaxf(m, v[j]);
    m = wredmax(m);
    float e[5], s = 0.f;
    #pragma unroll
    for (int j = 0; j < 4; j++) { e[j] = __expf(v[j] - m); s += e[j]; }
    e[4] = v4 ? __expf(v[4] - m) : 0.f; s += e[4];
    s = wredsum(s);
    const float inv = 1.f / s;

    float t[5];
    #pragma unroll
    for (int j = 0; j < 4; j++) t[j] = e[j] * inv * dr[lane + j * 64];
    t[4] = v4 ? e[4] * inv * dr[256 + lane] : -1e30f;
    float m2 = t[0];
    #pragma unroll
    for (int j = 1; j < 5; j++) m2 = fmaxf(m2, t[j]);
    m2 = wredmax(m2);
    float e2[5], s2 = 0.f;
    #pragma unroll
    for (int j = 0; j < 4; j++) { e2[j] = __expf(t[j] - m2); s2 += e2[j]; }
    e2[4] = v4 ? __expf(t[4] - m2) : 0.f; s2 += e2[4];
    s2 = wredsum(s2);
    const float inv2 = 1.f / s2;

    #pragma unroll
    for (int j = 0; j < 5; j++) {
        if (j == 4 && !v4) break;
        int col = (j == 4) ? 256 + lane : lane + j * 64;
        float pv = e2[j] * inv2;
        ushort h = f2bf(pv);
        F2h[row * NSP + col] = h;
        F2l[row * NSP + col] = f2bf(pv - bf2f(h));
    }
}

// ---------------- SM2: channel softmax (rows of 1024) -> bf16 ---------------
__global__ __launch_bounds__(256) void softmax_channel(
        const float* __restrict__ L, ushort* __restrict__ P)
{
    const int w = threadIdx.x >> 6, lane = threadIdx.x & 63;
    const size_t row = (size_t)blockIdx.x * 4 + w;
    const float4* fr = (const float4*)(L + row * C_);
    float4 v[4];
    #pragma unroll
    for (int j = 0; j < 4; j++) v[j] = fr[j * 64 + lane];
    float m = -1e30f;
    #pragma unroll
    for (int j = 0; j < 4; j++)
        m = fmaxf(m, fmaxf(fmaxf(v[j].x, v[j].y), fmaxf(v[j].z, v[j].w)));
    m = wredmax(m);
    float4 e[4]; float s = 0.f;
    #pragma unroll
    for (int j = 0; j < 4; j++) {
        e[j].x = __expf(v[j].x - m); e[j].y = __expf(v[j].y - m);
        e[j].z = __expf(v[j].z - m); e[j].w = __expf(v[j].w - m);
        s += e[j].x + e[j].y + e[j].z + e[j].w;
    }
    s = wredsum(s);
    const float inv = 1.f / s;
    ushort4* orow = (ushort4*)(P + row * C_);
    #pragma unroll
    for (int j = 0; j < 4; j++) {
        ushort4 o;
        o.x = f2bf(e[j].x * inv); o.y = f2bf(e[j].y * inv);
        o.z = f2bf(e[j].z * inv); o.w = f2bf(e[j].w * inv);
        orow[j * 64 + lane] = o;
    }
}

// ---------------- BN stats -> fused affine (a=rs*gamma, b=beta-mean*a) ------
template<int DT>   // 0=f32, 2=f16
__global__ __launch_bounds__(256) void bn_stats(
        const void* __restrict__ in, const float* __restrict__ gamma,
        const float* __restrict__ beta, float* __restrict__ a, float* __restrict__ bv)
{
    const int c = blockIdx.x;
    float s = 0.f, ss = 0.f;
    for (int i = threadIdx.x; i < B_ * NSP; i += 256) {
        int b = i / NSP, n = i - b * NSP;
        size_t idx = ((size_t)b * C_ + c) * NSP + n;
        float v = (DT == 0) ? ((const float*)in)[idx]
                            : __half2float(((const __half*)in)[idx]);
        s += v; ss += v * v;
    }
    __shared__ float ls[256], lss[256];
    ls[threadIdx.x] = s; lss[threadIdx.x] = ss;
    __syncthreads();
    for (int o = 128; o >= 1; o >>= 1) {
        if (threadIdx.x < o) { ls[threadIdx.x] += ls[threadIdx.x + o];
                               lss[threadIdx.x] += lss[threadIdx.x + o]; }
        __syncthreads();
    }
    if (threadIdx.x == 0) {
        const float invn = 1.f / (float)(B_ * NSP);
        float mean = ls[0] * invn;
        float var  = lss[0] * invn - mean * mean;
        float rs   = rsqrtf(var + 1e-5f);
        float av   = rs * gamma[c];
        a[c] = av; bv[c] = beta[c] - mean * av;
    }
}

// ---------------- z-stage: z = y*a1+b1+x -> zh, zl (zl aliases y!) ----------
__global__ __launch_bounds__(256) void z_stage(
        const __half* y, const float* __restrict__ x, const float* __restrict__ st,
        ushort* __restrict__ zh, ushort* zl)
{
    const int c0 = blockIdx.x * 32, b = blockIdx.y;
    const size_t base = ((size_t)b * C_ + c0) * NSP;
    for (int i = threadIdx.x; i < 32 * NSP; i += 256) {
        int cl = i / NSP, nl = i - cl * NSP;
        size_t idx = base + (size_t)cl * NSP + nl;
        float v = __half2float(y[idx]) * st[c0 + cl] + st[C_ + c0 + cl] + x[idx];
        ushort h = f2bf(v);
        zh[idx] = h;
        zl[idx] = f2bf(v - bf2f(h));   // same 2-byte slot as y[idx]: race-free
    }
}

// ---------------- P3: zh (c-major) -> zT (n-major) per chunk ----------------
__global__ __launch_bounds__(256) void ztrans(
        const ushort* __restrict__ zh, ushort* __restrict__ zT, int b0)
{
    __shared__ ushort lds[32][290];
    const int c0 = blockIdx.x * 32, bb = blockIdx.y, b = b0 + bb;
    const size_t gbase = ((size_t)b * C_ + c0) * NSP;
    for (int i = threadIdx.x; i < 32 * NSP; i += 256) {
        int cl = i / NSP, nl = i - cl * NSP;
        lds[cl][nl] = zh[gbase + (size_t)cl * NSP + nl];
    }
    __syncthreads();
    const size_t tbase = (size_t)bb * CN + c0;
    for (int i = threadIdx.x; i < NSP * 32; i += 256) {
        int nl = i >> 5, cl = i & 31;
        zT[tbase + (size_t)nl * C_ + cl] = lds[cl][nl];
    }
}

// ---------------- final: out = out*a2+b2 + (zh+zl) --------------------------
__global__ __launch_bounds__(256) void final_fuse(
        float* __restrict__ out, const ushort* __restrict__ zh,
        const ushort* zl, const float* __restrict__ st)
{
    const size_t n4 = NE / 4;
    const size_t stride = (size_t)gridDim.x * 256;
    for (size_t i = (size_t)blockIdx.x * 256 + threadIdx.x; i < n4; i += stride) {
        float4 v = ((float4*)out)[i];
        ushort4 h4 = ((const ushort4*)zh)[i];
        ushort4 l4 = ((const ushort4*)zl)[i];
        int c = (int)((i * 4 / NSP) % C_);
        float aa = st[c], bb = st[C_ + c];
        v.x = v.x * aa + bb + bf2f(h4.x) + bf2f(l4.x);
        v.y = v.y * aa + bb + bf2f(h4.y) + bf2f(l4.y);
        v.z = v.z * aa + bb + bf2f(h4.z) + bf2f(l4.z);
        v.w = v.w * aa + bb + bf2f(h4.w) + bf2f(l4.w);
        ((float4*)out)[i] = v;
    }
}

// ---------------------------------------------------------------------------
extern "C" void kernel_launch(void* const* d_in, const int* in_sizes, int n_in,
                              void* d_out, int out_size, void* d_ws, size_t ws_size,
                              hipStream_t stream)
{
    const float* x      = (const float*)d_in[0];
    const float* dis    = (const float*)d_in[1];
    const float* gamma1 = (const float*)d_in[2];
    const float* beta1  = (const float*)d_in[3];
    const float* gamma2 = (const float*)d_in[4];
    const float* beta2  = (const float*)d_in[5];
    float* out = (float*)d_out;
    char*  ws  = (char*)d_ws;

    // ---- workspace layout (peak ~261.1 MB; round-3 proved ws >= ~290 MB) ----
    const size_t SZ_BF = NE * 2;                  // 75,497,472
    const size_t o_y   = 0;                       // fp16 y; later zl (in-place)
    const size_t o_zh  = SZ_BF;                   // 75.5..151 MB
    const size_t o_c1  = 2 * SZ_BF;               // shared chunk region @151 MB
    // phase-1 sub-layout (BC1=16)
    const size_t c1_xh  = o_c1;
    const size_t c1_xl  = c1_xh + (size_t)BC1 * CN * 2;
    const size_t c1_xT  = c1_xl + (size_t)BC1 * CN * 2;
    const size_t c1_f   = c1_xT + (size_t)BC1 * CN * 2;
    const size_t c1_F2h = c1_f  + (size_t)BC1 * SP2 * 4;
    const size_t c1_F2l = c1_F2h + (size_t)BC1 * SP2 * 2;
    // phase-3 sub-layout (BC3=16), same region (phase-1 buffers dead)
    const size_t c3_L  = o_c1;
    const size_t c3_P  = c3_L + (size_t)BC3 * CC * 4;
    const size_t c3_zT = c3_P + (size_t)BC3 * CC * 2;
    const size_t o_st  = c3_zT + (size_t)BC3 * CN * 2;   // ~261.1 MB

    __half* y    = (__half*)(ws + o_y);
    ushort* zl   = (ushort*)(ws + o_y);    // in-place over y after z_stage
    ushort* zh   = (ushort*)(ws + o_zh);
    ushort* xh   = (ushort*)(ws + c1_xh);
    ushort* xl   = (ushort*)(ws + c1_xl);
    ushort* xT   = (ushort*)(ws + c1_xT);
    float*  fsp  = (float*) (ws + c1_f);
    ushort* F2h  = (ushort*)(ws + c1_F2h);
    ushort* F2l  = (ushort*)(ws + c1_F2l);
    float*  Lc   = (float*) (ws + c3_L);
    ushort* Pc   = (ushort*)(ws + c3_P);
    ushort* zTc  = (ushort*)(ws + c3_zT);
    float*  st1  = (float*) (ws + o_st);           // a1[1024], b1[1024]
    float*  st2  = (float*) (ws + o_st + 8192);    // a2[1024], b2[1024]

    // ---------------- Phase 1: spatial attention, chunked -------------------
    for (int b0 = 0; b0 < B_; b0 += BC1) {
        xsplit<<<dim3(32, BC1), 256, 0, stream>>>(x, xh, xl, xT, b0);
        // G1: gram of xT rows (K=1024); softmax margin ~31 -> plain bf16 OK
        gemm_nt<96, 96, 0, 1><<<dim3(3, 3, BC1), 256, 0, stream>>>(
            xT, xT, nullptr, nullptr, nullptr, nullptr, fsp,
            C_, NSP, CN, CN, SP2, 0.03125f);
        softmax_spatial<<<BC1 * NSP / 4, 256, 0, stream>>>(fsp, dis, F2h, F2l);
        // G2: y = (xh+xl).(F2h+F2l)^T, 3-pass split, single fp16 rounding
        gemm_nt<128, 96, 2, 3><<<dim3(3, 8, BC1), 256, 0, stream>>>(
            xh, F2h, xh, F2l, xl, F2h, (void*)(y + (size_t)b0 * CN),
            NSP, NSP, CN, SP2, CN, 1.0f);
    }

    // ---------------- Phase 2: BN1 + z = BN(y)+x -> zh, zl ------------------
    bn_stats<2><<<C_, 256, 0, stream>>>(y, gamma1, beta1, st1, st1 + C_);
    z_stage<<<dim3(32, B_), 256, 0, stream>>>(y, x, st1, zh, zl);

    // ---------------- Phase 3: channel attention, chunked -------------------
    for (int b0 = 0; b0 < B_; b0 += BC3) {
        const ushort* zhb = zh + (size_t)b0 * CN;
        const ushort* zlb = zl + (size_t)b0 * CN;
        // G3: L = Zh.Zh^T + Zh.Zl^T + Zl.Zh^T (split gram, fp32 logits)
        gemm_nt<128, 128, 0, 3><<<dim3(8, 8, BC3), 256, 0, stream>>>(
            zhb, zhb, zhb, zlb, zlb, zhb, Lc,
            NSP, C_, CN, CN, CC, 1.0f);
        softmax_channel<<<BC3 * 256, 256, 0, stream>>>(Lc, Pc);
        ztrans<<<dim3(32, BC3), 256, 0, stream>>>(zh, zTc, b0);
        // G4: y2 = P . zT (K=1024)
        gemm_nt<64, 96, 0, 1><<<dim3(3, 16, BC3), 256, 0, stream>>>(
            Pc, zTc, nullptr, nullptr, nullptr, nullptr,
            (void*)(out + (size_t)b0 * CN),
            C_, NSP, CC, CN, CN, 1.0f);
    }

    // ---------------- Phase 4: BN2 + final fuse -----------------------------
    bn_stats<0><<<C_, 256, 0, stream>>>(out, gamma2, beta2, st2, st2 + C_);
    final_fuse<<<2048, 256, 0, stream>>>(out, zh, zl, st2);
}